// Round 2
// baseline (233.315 us; speedup 1.0000x reference)
//
#include <hip/hip_runtime.h>

// FWHT over last dim 4096 of fp32 tensor, rows = total/4096.
// One wave (64 lanes) per row, one wave per block. Lane holds 64 fp32 in VGPRs.
// Stages: bits 0-5 in registers -> 64x64 transpose through a HALF-SIZE (32-row)
// LDS buffer in two chunks (8.7 KB/block -> 16 blocks/CU slot cap instead of
// 9 LDS-capped) -> bits 6-11 in registers -> scale 2^-39 -> coalesced nt store.
// Butterfly order matches reference exactly (h = 1..2048) -> bit-exact fp32.

constexpr int DIM = 4096;
constexpr int PITCH = 68;  // 64 + 4 pad; (m*68+lane)%32 = (4m+lane)%32 -> 2-way max (free)

__global__ __launch_bounds__(64, 4) void fwht4096_kernel(const float* __restrict__ x,
                                                         float* __restrict__ y) {
    __shared__ float buf[32 * PITCH];  // 8704 B, wave-private (1 wave/block)
    const int lane = threadIdx.x;      // 0..63
    const long long row = blockIdx.x;  // one row per block/wave

    float v[64];

    // ---- load: lane owns n = lane*64 + j, j = 0..63 (16 x float4, 1 KiB/lane-group) ----
    {
        const float4* src = reinterpret_cast<const float4*>(x + row * DIM + lane * 64);
#pragma unroll
        for (int q = 0; q < 16; ++q) {
            float4 t = src[q];
            v[4 * q + 0] = t.x;
            v[4 * q + 1] = t.y;
            v[4 * q + 2] = t.z;
            v[4 * q + 3] = t.w;
        }
    }

    // ---- phase 1: butterflies on bits 0..5 (register index j) ----
#pragma unroll
    for (int h = 1; h < 64; h <<= 1) {
#pragma unroll
        for (int i = 0; i < 64; i += 2 * h) {
#pragma unroll
            for (int k = 0; k < h; ++k) {
                float a = v[i + k];
                float b = v[i + k + h];
                v[i + k]     = a + b;
                v[i + k + h] = a - b;
            }
        }
    }

    // ---- transpose, chunk 0: rows (old-lane) 0..31 ----
    float w[64];  // transposed values: w[m] = value at n = m*64 + lane
    if (lane < 32) {
        float* wp = buf + lane * PITCH;
#pragma unroll
        for (int q = 0; q < 16; ++q) {
            float4 t = make_float4(v[4 * q], v[4 * q + 1], v[4 * q + 2], v[4 * q + 3]);
            reinterpret_cast<float4*>(wp)[q] = t;
        }
    }
    __syncthreads();  // 1 wave: just the lgkm drain, ~free
#pragma unroll
    for (int m = 0; m < 32; ++m) {
        w[m] = buf[m * PITCH + lane];
    }
    __syncthreads();

    // ---- transpose, chunk 1: rows (old-lane) 32..63 ----
    if (lane >= 32) {
        float* wp = buf + (lane - 32) * PITCH;
#pragma unroll
        for (int q = 0; q < 16; ++q) {
            float4 t = make_float4(v[4 * q], v[4 * q + 1], v[4 * q + 2], v[4 * q + 3]);
            reinterpret_cast<float4*>(wp)[q] = t;
        }
    }
    __syncthreads();
#pragma unroll
    for (int m = 0; m < 32; ++m) {
        w[32 + m] = buf[m * PITCH + lane];
    }

    // ---- phase 2: butterflies on bits 6..11 (register index m) ----
#pragma unroll
    for (int h = 1; h < 64; h <<= 1) {
#pragma unroll
        for (int i = 0; i < 64; i += 2 * h) {
#pragma unroll
            for (int k = 0; k < h; ++k) {
                float a = w[i + k];
                float b = w[i + k + h];
                w[i + k]     = a + b;
                w[i + k + h] = a - b;
            }
        }
    }

    // ---- scale + store: value m sits at n = m*64 + lane (256 B coalesced per m) ----
    const float scale = 0x1p-39f;  // 2^-(L(L+1)/4), L=12
    float* dst = y + row * DIM + lane;
#pragma unroll
    for (int m = 0; m < 64; ++m) {
        __builtin_nontemporal_store(w[m] * scale, dst + m * 64);
    }
}

extern "C" void kernel_launch(void* const* d_in, const int* in_sizes, int n_in,
                              void* d_out, int out_size, void* d_ws, size_t ws_size,
                              hipStream_t stream) {
    const float* x = (const float*)d_in[0];
    float* y = (float*)d_out;
    const int nrows = in_sizes[0] / DIM;  // 8192
    fwht4096_kernel<<<nrows, 64, 0, stream>>>(x, y);
}

// Round 4
// 229.971 us; speedup vs baseline: 1.0145x; 1.0145x over previous
//
#include <hip/hip_runtime.h>

// FWHT over last dim 4096 of fp32 tensor, rows = total/4096.
// One wave (64 lanes) per row, one wave per block.
//
// All global accesses are lane-contiguous (coalesced).
// Load dwordx4: instruction t covers bytes [t*1024,(t+1)*1024) of the row;
// lane holds v[4t+e] = element n = 256t + 4*lane + e.
// In-register bits of n: {0,1} (e) and {8..11} (t) -> 6 stages in registers.
// LDS transpose (padded A(n) = n + 4*(n>>8)) -> registers hold bits {2..7},
// lanes hold {0,1,8..11} -> 6 stages -> transpose back -> coalesced dwordx4
// stores. Stage order differs from reference (0,1,8..11,2..7) — Hadamard
// stages commute exactly; fp reordering error ~1e-15 << 1.4e-11 threshold.
//
// LDS bank behavior: b128 write/read at float-index 260t + 4*lane are fully
// contiguous (conflict-free); b32 side at e0 + 4r + 260g is exactly 2-way
// (free on CDNA4). 16,640 B LDS -> 9 blocks/CU.

constexpr int DIM = 4096;

typedef float vfloat4 __attribute__((ext_vector_type(4)));  // native vec: OK for nontemporal builtins

__global__ __launch_bounds__(64) void fwht4096_kernel(const float* __restrict__ x,
                                                      float* __restrict__ y) {
    __shared__ float buf[4160];        // A(n) = n + 4*(n>>8), n in [0,4096)
    const int lane = threadIdx.x;      // 0..63
    const int e0 = lane & 3;           // bits 0,1 of n during phase 2
    const int g  = lane >> 2;          // bits 8..11 of n during phase 2
    const long long row = blockIdx.x;

    float v[64];

    // ---- coalesced load: 16 x dwordx4, 1 KB contiguous per instruction ----
    {
        const vfloat4* src = reinterpret_cast<const vfloat4*>(x + row * DIM) + lane;
#pragma unroll
        for (int t = 0; t < 16; ++t) {
            vfloat4 q = src[t * 64];
            v[4 * t + 0] = q.x;
            v[4 * t + 1] = q.y;
            v[4 * t + 2] = q.z;
            v[4 * t + 3] = q.w;
        }
    }

    // ---- phase 1a: bits 0,1 (e dimension, in-register) ----
#pragma unroll
    for (int t = 0; t < 16; ++t) {
        float a0 = v[4 * t + 0], a1 = v[4 * t + 1];
        float a2 = v[4 * t + 2], a3 = v[4 * t + 3];
        float b0 = a0 + a1, b1 = a0 - a1;   // bit 0
        float b2 = a2 + a3, b3 = a2 - a3;
        v[4 * t + 0] = b0 + b2;             // bit 1
        v[4 * t + 1] = b1 + b3;
        v[4 * t + 2] = b0 - b2;
        v[4 * t + 3] = b1 - b3;
    }

    // ---- phase 1b: bits 8..11 (t dimension, in-register) ----
#pragma unroll
    for (int h = 1; h < 16; h <<= 1) {
#pragma unroll
        for (int i = 0; i < 16; i += 2 * h) {
#pragma unroll
            for (int k = 0; k < h; ++k) {
#pragma unroll
                for (int e = 0; e < 4; ++e) {
                    float a = v[4 * (i + k) + e];
                    float b = v[4 * (i + k + h) + e];
                    v[4 * (i + k) + e]     = a + b;
                    v[4 * (i + k + h) + e] = a - b;
                }
            }
        }
    }

    // ---- T1: registers -> LDS (b128, contiguous, conflict-free) ----
    // value n = 256t + 4*lane + e  ->  buf[A(n)] with A = 260t + 4*lane + e
#pragma unroll
    for (int t = 0; t < 16; ++t) {
        vfloat4 q = {v[4 * t + 0], v[4 * t + 1], v[4 * t + 2], v[4 * t + 3]};
        *reinterpret_cast<vfloat4*>(&buf[260 * t + 4 * lane]) = q;
    }
    __syncthreads();  // single-wave barrier: just the lgkm drain

    // ---- LDS -> registers: w[r] = n = e0 + 4r + 256g, A = e0 + 4r + 260g ----
    float w[64];
#pragma unroll
    for (int r = 0; r < 64; ++r) {
        w[r] = buf[e0 + 4 * r + 260 * g];   // 2-way bank aliasing: free
    }

    // ---- phase 2: bits 2..7 (r dimension, in-register) ----
#pragma unroll
    for (int h = 1; h < 64; h <<= 1) {
#pragma unroll
        for (int i = 0; i < 64; i += 2 * h) {
#pragma unroll
            for (int k = 0; k < h; ++k) {
                float a = w[i + k];
                float b = w[i + k + h];
                w[i + k]     = a + b;
                w[i + k + h] = a - b;
            }
        }
    }

    __syncthreads();  // WAR guard before overwrite

    // ---- T2: registers -> LDS (same addressing, 2-way) ----
#pragma unroll
    for (int r = 0; r < 64; ++r) {
        buf[e0 + 4 * r + 260 * g] = w[r];
    }
    __syncthreads();

    // ---- LDS -> registers (b128) + scale + coalesced dwordx4 nt-store ----
    const float scale = 0x1p-39f;  // 2^-(L(L+1)/4), L = 12
    vfloat4* dst = reinterpret_cast<vfloat4*>(y + row * DIM) + lane;
#pragma unroll
    for (int t = 0; t < 16; ++t) {
        vfloat4 q = *reinterpret_cast<const vfloat4*>(&buf[260 * t + 4 * lane]);
        q *= scale;
        __builtin_nontemporal_store(q, &dst[t * 64]);
    }
}

extern "C" void kernel_launch(void* const* d_in, const int* in_sizes, int n_in,
                              void* d_out, int out_size, void* d_ws, size_t ws_size,
                              hipStream_t stream) {
    const float* x = (const float*)d_in[0];
    float* y = (float*)d_out;
    const int nrows = in_sizes[0] / DIM;  // 8192
    fwht4096_kernel<<<nrows, 64, 0, stream>>>(x, y);
}